// Round 1
// baseline (3242.099 us; speedup 1.0000x reference)
//
#include <hip/hip_runtime.h>
#include <hip/hip_bf16.h>
#include <math.h>

#define S_LEN   800
#define SP_LEN  896              // padded to 7*128 for K/V
#define C_DIM   768
#define NHEAD   12
#define DHEAD   64
#define HID_DIM 3072
#define BATCH   4
#define NTOK    (BATCH * S_LEN)   // 3200
#define DEPTH_N 12

using bf16x8 = __attribute__((ext_vector_type(8))) short;
using f32x4  = __attribute__((ext_vector_type(4))) float;

__device__ inline short f2bf(float x) {
    unsigned u = __builtin_bit_cast(unsigned, x);
    u += 0x7fff + ((u >> 16) & 1);          // RNE
    return (short)(u >> 16);
}
__device__ inline float bf2f(short x) {
    unsigned u = ((unsigned)(unsigned short)x) << 16;
    return __builtin_bit_cast(float, u);
}

typedef const __attribute__((address_space(1))) void* gas_ptr;
typedef __attribute__((address_space(3))) void* las_ptr;
__device__ inline void async_copy16(const void* g, void* l) {
    __builtin_amdgcn_global_load_lds((gas_ptr)g, (las_ptr)l, 16, 0, 0);
}

// ---------------------------------------------------------------------------
// Batched transpose + convert for all 4 per-layer weights.
// W fp32 [K][N] -> Wt bf16 [N][K].
// ---------------------------------------------------------------------------
struct TP4 {
    const float *qw, *pw, *f1, *f2;
    short *wq, *wp, *w1, *w2;
};

template <int K, int N>
__device__ __forceinline__ void tc_tile(const float* __restrict__ W,
                                        short* __restrict__ Wt, int t) {
    __shared__ float tile[32][33];
    int nb = t % (N / 32), kb = t / (N / 32);
    int k0 = kb * 32, n0 = nb * 32;
    int tx = threadIdx.x & 31, ty = threadIdx.x >> 5;   // 32 x 8
#pragma unroll
    for (int i = ty; i < 32; i += 8)
        tile[i][tx] = W[(size_t)(k0 + i) * N + n0 + tx];
    __syncthreads();
#pragma unroll
    for (int i = ty; i < 32; i += 8)
        Wt[(size_t)(n0 + i) * K + k0 + tx] = f2bf(tile[tx][i]);
}

__global__ __launch_bounds__(256)
void transpose4_kernel(TP4 p) {
    int t = blockIdx.x;
    if (t < 1728)          tc_tile<768, 2304>(p.qw, p.wq, t);            // 24*72
    else if (t < 2304)     tc_tile<768, 768>(p.pw, p.wp, t - 1728);      // 24*24
    else if (t < 4608)     tc_tile<768, 3072>(p.f1, p.w1, t - 2304);     // 24*96
    else                   tc_tile<3072, 768>(p.f2, p.w2, t - 4608);     // 96*24
}

__global__ void convert_bf_kernel(const float* __restrict__ a, short* __restrict__ o, int n) {
    int i = blockIdx.x * 256 + threadIdx.x;
    if (i < n) o[i] = f2bf(a[i]);
}

// ---------------------------------------------------------------------------
// im2col (bf16 out) for the dual patch embed.
// ---------------------------------------------------------------------------
__global__ void im2col_kernel(const float* __restrict__ x, short* __restrict__ A) {
    int idx = blockIdx.x * 256 + threadIdx.x;          // 3200*768
    if (idx >= NTOK * 768) return;
    int kk = idx % 768;
    int s  = (idx / 768) % S_LEN;
    int b  = idx / (768 * S_LEN);
    int c  = kk / 256;
    int i  = (kk / 16) % 16;
    int j  = kk % 16;
    int half = s / 400, ss = s % 400;
    int hg = ss / 20, wg = ss % 20;
    int ch = half * 3 + c;
    A[idx] = f2bf(x[((size_t)(b * 6 + ch) * 320 + hg * 16 + i) * 320 + wg * 16 + j]);
}

// ---------------------------------------------------------------------------
// bf16 MFMA GEMM (128-tile, 1-phase) — kept for proj / fc2 / embed where
// N=768 gives too few 256-blocks.
// ---------------------------------------------------------------------------
template <int BN, bool GELU, bool RES, bool OBF>
__global__ __launch_bounds__(256)
void gemm_mfma(const short* __restrict__ A, const short* __restrict__ Bt,
               const float* __restrict__ bias, const float* __restrict__ res,
               void* __restrict__ Cout, int M, int N, int K) {
    constexpr int BM = 128, BK = 64;
    constexpr int TI = (BN == 128) ? 4 : 2;
    constexpr int TJ = 4;
    constexpr int ACALLS = BM * BK / (8 * 64);   // 16
    constexpr int BCALLS = BN * BK / (8 * 64);   // 16 or 8

    __shared__ __align__(16) short As[BM * BK];
    __shared__ __align__(16) short Bs[BN * BK];

    int tid = threadIdx.x;
    int w = tid >> 6, lane = tid & 63;
    int m0 = blockIdx.y * BM, n0 = blockIdx.x * BN;

    int wr = (BN == 128) ? (w >> 1) * 64 : w * 32;
    int wc = (BN == 128) ? (w & 1) * 64 : 0;

    f32x4 acc[TI][TJ];
#pragma unroll
    for (int i = 0; i < TI; ++i)
#pragma unroll
        for (int j = 0; j < TJ; ++j)
            acc[i][j] = (f32x4){0.f, 0.f, 0.f, 0.f};

    int lc = lane & 15, lq = lane >> 4;

    for (int k0 = 0; k0 < K; k0 += BK) {
#pragma unroll
        for (int j = w; j < ACALLS; j += 4) {
            int c = j * 64 + lane;
            int row = c >> 3, p = c & 7, q = p ^ (row & 7);
            async_copy16(A + (size_t)(m0 + row) * K + k0 + q * 8, As + j * 512);
        }
#pragma unroll
        for (int j = w; j < BCALLS; j += 4) {
            int c = j * 64 + lane;
            int row = c >> 3, p = c & 7, q = p ^ (row & 7);
            async_copy16(Bt + (size_t)(n0 + row) * K + k0 + q * 8, Bs + j * 512);
        }
        __syncthreads();

#pragma unroll
        for (int h = 0; h < 2; ++h) {
            bf16x8 afrag[TI], bfrag[TJ];
#pragma unroll
            for (int i = 0; i < TI; ++i) {
                int row = wr + i * 16 + lc;
                afrag[i] = *(const bf16x8*)(As + row * 64 + ((((h << 2) | lq)) ^ (row & 7)) * 8);
            }
#pragma unroll
            for (int j = 0; j < TJ; ++j) {
                int col = wc + j * 16 + lc;
                bfrag[j] = *(const bf16x8*)(Bs + col * 64 + ((((h << 2) | lq)) ^ (col & 7)) * 8);
            }
#pragma unroll
            for (int i = 0; i < TI; ++i)
#pragma unroll
                for (int j = 0; j < TJ; ++j)
                    acc[i][j] = __builtin_amdgcn_mfma_f32_16x16x32_bf16(
                        afrag[i], bfrag[j], acc[i][j], 0, 0, 0);
        }
        __syncthreads();
    }

    int rbase = lq * 4;
#pragma unroll
    for (int i = 0; i < TI; ++i)
#pragma unroll
        for (int j = 0; j < TJ; ++j)
#pragma unroll
            for (int r = 0; r < 4; ++r) {
                int m = m0 + wr + i * 16 + rbase + r;
                int n = n0 + wc + j * 16 + lc;
                float v = acc[i][j][r] + bias[n];
                if (RES) v += res[(size_t)m * N + n];
                if (GELU) v = 0.5f * v * (1.0f + erff(v * 0.70710678118654752f));
                if (OBF) ((short*)Cout)[(size_t)m * N + n] = f2bf(v);
                else     ((float*)Cout)[(size_t)m * N + n] = v;
            }
}

// ---------------------------------------------------------------------------
// 256x256 8-wave pipelined GEMM (T2+T3+T4+T5 schedule), bf16 out.
// BK=64 split into two K=32 planes per operand; double-buffered LDS (128 KiB).
// 4 phases per K-tile: {kk0,j01} {kk0,j23} {kk1,j01} {kk1,j23}; each phase
// stages one half-tile of tile t+1; vmcnt(4) waits only at phases 1 and 3 —
// every wait covers loads issued >=2 phases earlier. No vmcnt(0) in the loop.
//
// LDS plane layout (per K-half plane, 256 rows x 32 bf16 = 16 KiB):
//   chunk-in-granule cw(r,lq) = r*4 + ((lq + (r>>1)) & 3), granule = 8 rows.
//   -> a 16-lane frag-read group hits 8 distinct bank-quads (conflict-free
//      b128). Stage writes LDS linearly; global src pre-permuted inversely
//      (lq = (s - (r>>1)) & 3), per Guideline rule #21.
// ---------------------------------------------------------------------------
template <bool GELU>
__global__ __launch_bounds__(512, 2)
void gemm256(const short* __restrict__ A, const short* __restrict__ Bt,
             const float* __restrict__ bias, short* __restrict__ Cout,
             int M, int N, int K) {
    __shared__ __align__(16) short sm[65536];   // 2 bufs x (A 16384 + B 16384) shorts

    const int tid = threadIdx.x;
    const int w = tid >> 6, lane = tid & 63;
    const int lc = lane & 15, lq = lane >> 4;
    const int m0 = blockIdx.y * 256, n0 = blockIdx.x * 256;
    const int wr = (w >> 2) * 128;   // 2 row-halves of waves
    const int wc = (w & 3) * 64;     // 4 col-groups of waves

    f32x4 acc[8][4];
#pragma unroll
    for (int i = 0; i < 8; ++i)
#pragma unroll
        for (int j = 0; j < 4; ++j) acc[i][j] = (f32x4){0.f, 0.f, 0.f, 0.f};

    // staging geometry: one half-tile (16 KiB plane) = 16 wave-calls; 2 per wave
    const int c0 = w * 64 + lane;
    const int c1 = (8 + w) * 64 + lane;
    const int row0 = c0 >> 2, row1 = c1 >> 2;
    const int lqq0 = ((c0 & 3) - ((row0 & 7) >> 1)) & 3;
    const int lqq1 = ((c1 & 3) - ((row1 & 7) >> 1)) & 3;
    const int dst0 = w * 512;          // shorts within plane (wave-uniform)
    const int dst1 = (8 + w) * 512;

    // fragment read offsets (shorts within plane)
    int offA[8], offB[4];
#pragma unroll
    for (int i = 0; i < 8; ++i) {
        int row = wr + i * 16 + lc, r = row & 7;
        offA[i] = (row >> 3) * 256 + (r * 4 + ((lq + (r >> 1)) & 3)) * 8;
    }
#pragma unroll
    for (int j = 0; j < 4; ++j) {
        int col = wc + j * 16 + lc, r = col & 7;
        offB[j] = (col >> 3) * 256 + (r * 4 + ((lq + (r >> 1)) & 3)) * 8;
    }

    const int NT = K >> 6;

    // sel: 0=A-Klo 1=B-Klo 2=A-Khi 3=B-Khi ; nb = destination buffer
    auto stage = [&](int tsrc, int sel, int nb) {
        int kk = sel >> 1;
        const short* src = (sel & 1) ? Bt : A;
        int brow = (sel & 1) ? n0 : m0;
        short* dstp = sm + nb * 32768 + ((sel & 1) ? 16384 : 0) + kk * 8192;
        int kbase = tsrc * 64 + kk * 32;
        async_copy16(src + (size_t)(brow + row0) * K + kbase + lqq0 * 8, dstp + dst0);
        async_copy16(src + (size_t)(brow + row1) * K + kbase + lqq1 * 8, dstp + dst1);
    };

#define MFMA16(J0, J1)                                                              \
    _Pragma("unroll")                                                               \
    for (int i = 0; i < 8; ++i) {                                                   \
        acc[i][J0] = __builtin_amdgcn_mfma_f32_16x16x32_bf16(af[i], bfr[0],         \
                                                             acc[i][J0], 0, 0, 0); \
        acc[i][J1] = __builtin_amdgcn_mfma_f32_16x16x32_bf16(af[i], bfr[1],         \
                                                             acc[i][J1], 0, 0, 0); \
    }

    // prologue: stage tile 0 fully; wait Klo halves (allow Khi outstanding)
    stage(0, 0, 0); stage(0, 1, 0); stage(0, 2, 0); stage(0, 3, 0);
    asm volatile("s_waitcnt vmcnt(4)" ::: "memory");
    __builtin_amdgcn_s_barrier();

    for (int t = 0; t < NT; ++t) {
        const int nb = (t + 1) & 1;
        const int tsrc = (t + 1 < NT) ? t + 1 : t;   // clamp: dup-stage into other buf
        const short* Abase = sm + (t & 1) * 32768;
        const short* Bbase = Abase + 16384;
        bf16x8 af[8], bfr[2];

        // ---- phase 0: kk=0, cols j0,j1
#pragma unroll
        for (int i = 0; i < 8; ++i) af[i] = *(const bf16x8*)(Abase + offA[i]);
        bfr[0] = *(const bf16x8*)(Bbase + offB[0]);
        bfr[1] = *(const bf16x8*)(Bbase + offB[1]);
        stage(tsrc, 0, nb);
        __builtin_amdgcn_s_barrier();
        __builtin_amdgcn_s_setprio(1);
        MFMA16(0, 1)
        __builtin_amdgcn_s_setprio(0);
        __builtin_amdgcn_s_barrier();

        // ---- phase 1: kk=0, cols j2,j3  (+wait: Khi of tile t landed)
        bfr[0] = *(const bf16x8*)(Bbase + offB[2]);
        bfr[1] = *(const bf16x8*)(Bbase + offB[3]);
        stage(tsrc, 1, nb);
        asm volatile("s_waitcnt vmcnt(4)" ::: "memory");
        __builtin_amdgcn_s_barrier();
        __builtin_amdgcn_s_setprio(1);
        MFMA16(2, 3)
        __builtin_amdgcn_s_setprio(0);
        __builtin_amdgcn_s_barrier();

        // ---- phase 2: kk=1, cols j0,j1
#pragma unroll
        for (int i = 0; i < 8; ++i) af[i] = *(const bf16x8*)(Abase + 8192 + offA[i]);
        bfr[0] = *(const bf16x8*)(Bbase + 8192 + offB[0]);
        bfr[1] = *(const bf16x8*)(Bbase + 8192 + offB[1]);
        stage(tsrc, 2, nb);
        __builtin_amdgcn_s_barrier();
        __builtin_amdgcn_s_setprio(1);
        MFMA16(0, 1)
        __builtin_amdgcn_s_setprio(0);
        __builtin_amdgcn_s_barrier();

        // ---- phase 3: kk=1, cols j2,j3  (+wait: Klo of tile t+1 landed)
        bfr[0] = *(const bf16x8*)(Bbase + 8192 + offB[2]);
        bfr[1] = *(const bf16x8*)(Bbase + 8192 + offB[3]);
        stage(tsrc, 3, nb);
        asm volatile("s_waitcnt vmcnt(4)" ::: "memory");
        __builtin_amdgcn_s_barrier();
        __builtin_amdgcn_s_setprio(1);
        MFMA16(2, 3)
        __builtin_amdgcn_s_setprio(0);
        __builtin_amdgcn_s_barrier();
    }
#undef MFMA16

    // epilogue (M-guard for the padded last row-block)
#pragma unroll
    for (int i = 0; i < 8; ++i)
#pragma unroll
        for (int j = 0; j < 4; ++j)
#pragma unroll
            for (int r = 0; r < 4; ++r) {
                int m = m0 + wr + i * 16 + lq * 4 + r;
                if (m < M) {
                    int n = n0 + wc + j * 16 + lc;
                    float v = acc[i][j][r] + bias[n];
                    if (GELU) v = 0.5f * v * (1.0f + erff(v * 0.70710678118654752f));
                    Cout[(size_t)m * N + n] = f2bf(v);
                }
            }
}

// ---------------------------------------------------------------------------
// LayerNorm (unchanged)
// ---------------------------------------------------------------------------
template <bool OBF>
__global__ __launch_bounds__(256)
void ln_kernel(const float* __restrict__ x, const float* __restrict__ g,
               const float* __restrict__ bta, void* __restrict__ yv) {
    int row = blockIdx.x;
    const float* xr = x + (size_t)row * C_DIM;
    int tid = threadIdx.x;

    float v0 = xr[tid], v1 = xr[tid + 256], v2 = xr[tid + 512];
    float s  = v0 + v1 + v2;
    float sq = v0 * v0 + v1 * v1 + v2 * v2;
#pragma unroll
    for (int off = 32; off; off >>= 1) {
        s  += __shfl_down(s, off);
        sq += __shfl_down(sq, off);
    }
    __shared__ float red1[4], red2[4];
    __shared__ float mean_s, rstd_s;
    int wv = tid / 64, lane = tid % 64;
    if (lane == 0) { red1[wv] = s; red2[wv] = sq; }
    __syncthreads();
    if (tid == 0) {
        float S1 = red1[0] + red1[1] + red1[2] + red1[3];
        float S2 = red2[0] + red2[1] + red2[2] + red2[3];
        float m = S1 / (float)C_DIM;
        float var = S2 / (float)C_DIM - m * m;
        mean_s = m;
        rstd_s = rsqrtf(var + 1e-6f);
    }
    __syncthreads();
    float m = mean_s, r = rstd_s;
    float o0 = (v0 - m) * r * g[tid]       + bta[tid];
    float o1 = (v1 - m) * r * g[tid + 256] + bta[tid + 256];
    float o2 = (v2 - m) * r * g[tid + 512] + bta[tid + 512];
    if (OBF) {
        short* yr = (short*)yv + (size_t)row * C_DIM;
        yr[tid] = f2bf(o0); yr[tid + 256] = f2bf(o1); yr[tid + 512] = f2bf(o2);
    } else {
        float* yr = (float*)yv + (size_t)row * C_DIM;
        yr[tid] = o0; yr[tid + 256] = o1; yr[tid + 512] = o2;
    }
}

// ---------------------------------------------------------------------------
// RoPE + split from bf16 qkv (tok, 2304) ->
//   qb/kb: (bh, s[896], dh) bf16 (q pre-scaled by 0.125*log2e), vtb: (bh, dh, s[896])
// ---------------------------------------------------------------------------
__global__ __launch_bounds__(256)
void rope_qkv_kernel(const short* __restrict__ qkv, short* __restrict__ qb,
                     short* __restrict__ kb, short* __restrict__ vtb) {
    int st = blockIdx.x;           // 0..13
    int bh = blockIdx.y;           // 0..47
    int b = bh / NHEAD, h = bh % NHEAD;
    int s0 = st * 64;

    __shared__ __align__(16) short vlds[64][72];

    int tid = threadIdx.x;
    int sl = tid >> 2;             // s row within tile
    int dc = (tid & 3) * 16;       // d chunk base
    int s = s0 + sl;

    short qo[16], ko[16];
    if (s < S_LEN) {
        const short* base = qkv + ((size_t)(b * S_LEN + s)) * (3 * C_DIM) + h * DHEAD + dc;
        short qsh[16], ksh[16], vsh[16];
        *(bf16x8*)(qsh)     = *(const bf16x8*)(base);
        *(bf16x8*)(qsh + 8) = *(const bf16x8*)(base + 8);
        *(bf16x8*)(ksh)     = *(const bf16x8*)(base + C_DIM);
        *(bf16x8*)(ksh + 8) = *(const bf16x8*)(base + C_DIM + 8);
        *(bf16x8*)(vsh)     = *(const bf16x8*)(base + 2 * C_DIM);
        *(bf16x8*)(vsh + 8) = *(const bf16x8*)(base + 2 * C_DIM + 8);
        float qv[16], kv[16];
#pragma unroll
        for (int i = 0; i < 16; ++i) { qv[i] = bf2f(qsh[i]); kv[i] = bf2f(ksh[i]); }
#pragma unroll
        for (int i = 0; i < 16; ++i) {
            int d = dc + i;
            float ang = (float)s * exp2f(-(float)(d & 31) * 0.41524101186092029f); // log2(1e4)/16
            float c = cosf(ang), sn = sinf(ang);
            float sign = (i & 1) ? 1.0f : -1.0f;
            qo[i] = f2bf((qv[i] * c + sign * qv[i ^ 1] * sn) * 0.18033688011112042f);
            ko[i] = f2bf(kv[i] * c + sign * kv[i ^ 1] * sn);
        }
        *(bf16x8*)&vlds[sl][dc]     = *(bf16x8*)(vsh);
        *(bf16x8*)&vlds[sl][dc + 8] = *(bf16x8*)(vsh + 8);
    } else {
#pragma unroll
        for (int i = 0; i < 16; ++i) { qo[i] = 0; ko[i] = 0; vlds[sl][dc + i] = 0; }
    }
    {
        short* qd = qb + ((size_t)bh * SP_LEN + s) * DHEAD + dc;
        short* kd = kb + ((size_t)bh * SP_LEN + s) * DHEAD + dc;
        *(bf16x8*)(qd)     = *(bf16x8*)(qo);
        *(bf16x8*)(qd + 8) = *(bf16x8*)(qo + 8);
        *(bf16x8*)(kd)     = *(bf16x8*)(ko);
        *(bf16x8*)(kd + 8) = *(bf16x8*)(ko + 8);
    }
    __syncthreads();
    {
        int dr = tid >> 2, sc = (tid & 3) * 16;
        short vo[16];
#pragma unroll
        for (int i = 0; i < 16; ++i) vo[i] = vlds[sc + i][dr];
        short* vd = vtb + ((size_t)bh * DHEAD + dr) * SP_LEN + s0 + sc;
        *(bf16x8*)(vd)     = *(bf16x8*)(vo);
        *(bf16x8*)(vd + 8) = *(bf16x8*)(vo + 8);
    }
}

// ---------------------------------------------------------------------------
// Flash attention, bf16 MFMA, K-tile=128, XOR-swizzled LDS. (unchanged)
// ---------------------------------------------------------------------------
__global__ __launch_bounds__(256)
void attn_mfma_kernel(const short* __restrict__ qb, const short* __restrict__ kb,
                      const short* __restrict__ vtb, short* __restrict__ o) {
    int qt = blockIdx.x;           // 0..12
    int bh = blockIdx.y;           // 0..47
    int b = bh / NHEAD, h = bh % NHEAD;
    int m0 = qt * 64;

    __shared__ __align__(16) short Qs[64 * 64];
    __shared__ __align__(16) short Ks[128 * 64];
    __shared__ __align__(16) short Vts[64 * 128];
    __shared__ __align__(16) short Ps[64 * 136];

    int tid = threadIdx.x;
    int w = tid >> 6, lane = tid & 63;
    int lc = lane & 15, lq = lane >> 4;
    int kq = lq * 8;

    const short* qbase = qb + (size_t)bh * SP_LEN * DHEAD;
    const short* kbase = kb + (size_t)bh * SP_LEN * DHEAD;
    const short* vbase = vtb + (size_t)bh * DHEAD * SP_LEN;

    f32x4 oacc[4];
#pragma unroll
    for (int t = 0; t < 4; ++t) oacc[t] = (f32x4){0.f, 0.f, 0.f, 0.f};
    float mrow[4] = {-3.0e38f, -3.0e38f, -3.0e38f, -3.0e38f};
    float lrow[4] = {0.f, 0.f, 0.f, 0.f};

    // stage Q once (swizzled)
#pragma unroll
    for (int j = w; j < 8; j += 4) {
        int c = j * 64 + lane;
        int row = c >> 3, p = c & 7, q = p ^ (row & 7);
        async_copy16(qbase + (size_t)(m0 + row) * DHEAD + q * 8, Qs + j * 512);
    }

    for (int it = 0; it < 7; ++it) {
        int kt = it * 128;
#pragma unroll
        for (int j = w; j < 16; j += 4) {
            int c = j * 64 + lane;
            int row = c >> 3, p = c & 7, q = p ^ (row & 7);
            async_copy16(kbase + (size_t)(kt + row) * DHEAD + q * 8, Ks + j * 512);
        }
#pragma unroll
        for (int j = w; j < 16; j += 4) {
            int c = j * 64 + lane;
            int d = c >> 4, p = c & 15, sq = p ^ (d & 15);
            async_copy16(vbase + (size_t)d * SP_LEN + kt + sq * 8, Vts + j * 512);
        }
        __syncthreads();

        int nt = (it < 6) ? 8 : 2;     // valid 16-col tiles

        int qrow = w * 16 + lc;
        bf16x8 aq0 = *(const bf16x8*)(Qs + qrow * 64 + ((lq) ^ (qrow & 7)) * 8);
        bf16x8 aq1 = *(const bf16x8*)(Qs + qrow * 64 + ((4 | lq) ^ (qrow & 7)) * 8);

        f32x4 sacc[8];
        for (int t = 0; t < nt; ++t) {
            int kr = t * 16 + lc;
            bf16x8 bk0 = *(const bf16x8*)(Ks + kr * 64 + ((lq) ^ (kr & 7)) * 8);
            bf16x8 bk1 = *(const bf16x8*)(Ks + kr * 64 + ((4 | lq) ^ (kr & 7)) * 8);
            f32x4 z = (f32x4){0.f, 0.f, 0.f, 0.f};
            z = __builtin_amdgcn_mfma_f32_16x16x32_bf16(aq0, bk0, z, 0, 0, 0);
            z = __builtin_amdgcn_mfma_f32_16x16x32_bf16(aq1, bk1, z, 0, 0, 0);
            sacc[t] = z;
        }

        float rmax[4];
#pragma unroll
        for (int r = 0; r < 4; ++r) {
            float m = sacc[0][r];
            for (int t = 1; t < nt; ++t) m = fmaxf(m, sacc[t][r]);
            rmax[r] = m;
        }
#pragma unroll
        for (int off = 1; off < 16; off <<= 1)
#pragma unroll
            for (int r = 0; r < 4; ++r)
                rmax[r] = fmaxf(rmax[r], __shfl_xor(rmax[r], off));

        float alpha[4], rsum[4] = {0.f, 0.f, 0.f, 0.f};
#pragma unroll
        for (int r = 0; r < 4; ++r) {
            float mnew = fmaxf(mrow[r], rmax[r]);
            alpha[r] = exp2f(mrow[r] - mnew);
            mrow[r] = mnew;
        }
        for (int t = 0; t < nt; ++t) {
#pragma unroll
            for (int r = 0; r < 4; ++r) {
                float p = exp2f(sacc[t][r] - mrow[r]);
                rsum[r] += p;
                Ps[(w * 16 + lq * 4 + r) * 136 + t * 16 + lc] = f2bf(p);
            }
        }
#pragma unroll
        for (int off = 1; off < 16; off <<= 1)
#pragma unroll
            for (int r = 0; r < 4; ++r)
                rsum[r] += __shfl_xor(rsum[r], off);
#pragma unroll
        for (int r = 0; r < 4; ++r) lrow[r] = lrow[r] * alpha[r] + rsum[r];
#pragma unroll
        for (int t = 0; t < 4; ++t)
#pragma unroll
            for (int r = 0; r < 4; ++r) oacc[t][r] *= alpha[r];

        int nk = (nt == 8) ? 4 : 1;
        for (int kstep = 0; kstep < nk; ++kstep) {
            bf16x8 ap = *(const bf16x8*)(Ps + (w * 16 + lc) * 136 + kstep * 32 + kq);
#pragma unroll
            for (int t = 0; t < 4; ++t) {
                int dr = t * 16 + lc;
                bf16x8 bv = *(const bf16x8*)(Vts + dr * 128 + ((((kstep << 2) | lq)) ^ (dr & 15)) * 8);
                oacc[t] = __builtin_amdgcn_mfma_f32_16x16x32_bf16(ap, bv, oacc[t], 0, 0, 0);
            }
        }
        __syncthreads();
    }

    float inv_l[4];
#pragma unroll
    for (int r = 0; r < 4; ++r) inv_l[r] = 1.0f / lrow[r];
#pragma unroll
    for (int t = 0; t < 4; ++t)
#pragma unroll
        for (int r = 0; r < 4; ++r) {
            int row = w * 16 + lq * 4 + r;
            int s = m0 + row;
            if (s < S_LEN) {
                int n = t * 16 + lc;
                o[((size_t)(b * S_LEN + s)) * C_DIM + h * DHEAD + n] = f2bf(oacc[t][r] * inv_l[r]);
            }
        }
}

// ---------------------------------------------------------------------------
// Host launcher
// ---------------------------------------------------------------------------
extern "C" void kernel_launch(void* const* d_in, const int* in_sizes, int n_in,
                              void* d_out, int out_size, void* d_ws, size_t ws_size,
                              hipStream_t stream) {
    const float* x      = (const float*)d_in[0];
    const float* conv_w = (const float*)d_in[1];
    const float* conv_b = (const float*)d_in[2];
    const float* ln1_g  = (const float*)d_in[3];
    const float* ln1_b  = (const float*)d_in[4];
    const float* qkv_w  = (const float*)d_in[5];
    const float* qkv_b  = (const float*)d_in[6];
    const float* proj_w = (const float*)d_in[7];
    const float* proj_b = (const float*)d_in[8];
    const float* ln2_g  = (const float*)d_in[9];
    const float* ln2_b  = (const float*)d_in[10];
    const float* fc1_w  = (const float*)d_in[11];
    const float* fc1_b  = (const float*)d_in[12];
    const float* fc2_w  = (const float*)d_in[13];
    const float* fc2_b  = (const float*)d_in[14];
    const float* lnf_g  = (const float*)d_in[15];
    const float* lnf_b  = (const float*)d_in[16];

    const size_t NTC = (size_t)NTOK * C_DIM;
    const size_t HSD = (size_t)BATCH * NHEAD * SP_LEN * DHEAD;  // 2,752,512
    float* ws = (float*)d_ws;
    float* h       = ws;                              // (B,S,C) f32
    short* qkv_bf  = (short*)(h + NTC);               // (B,S,3C) bf16
    short* qb      = qkv_bf + (size_t)NTOK * 3 * C_DIM;
    short* kb      = qb + HSD;
    short* vtb     = kb + HSD;
    short* y_bf    = vtb + HSD;                       // (B,S,C) bf16
    short* big_bf  = y_bf + NTC;                      // (B,S,HID) bf16 / im2col
    short* wq      = big_bf + (size_t)NTOK * HID_DIM; // (3C, C) bf16
    short* wp      = wq + (size_t)3 * C_DIM * C_DIM;  // (C, C)
    short* w1      = wp + (size_t)C_DIM * C_DIM;      // (HID, C)
    short* w2      = w1 + (size_t)C_DIM * HID_DIM;    // (C, HID)
    short* embed_wt = w2 + (size_t)HID_DIM * C_DIM;   // (C, C)

    // ---- patch embed ----
    convert_bf_kernel<<<(768 * 768 + 255) / 256, 256, 0, stream>>>(conv_w, embed_wt, 768 * 768);
    im2col_kernel<<<(NTOK * 768 + 255) / 256, 256, 0, stream>>>(x, big_bf);
    gemm_mfma<64, false, false, false><<<dim3(C_DIM / 64, NTOK / 128), 256, 0, stream>>>(
        big_bf, embed_wt, conv_b, nullptr, h, NTOK, C_DIM, C_DIM);

    for (int l = 0; l < DEPTH_N; ++l) {
        const float* l1g = ln1_g + (size_t)l * C_DIM;
        const float* l1b = ln1_b + (size_t)l * C_DIM;
        const float* qw  = qkv_w + (size_t)l * C_DIM * 3 * C_DIM;
        const float* qbs = qkv_b + (size_t)l * 3 * C_DIM;
        const float* pw  = proj_w + (size_t)l * C_DIM * C_DIM;
        const float* pb  = proj_b + (size_t)l * C_DIM;
        const float* l2g = ln2_g + (size_t)l * C_DIM;
        const float* l2b = ln2_b + (size_t)l * C_DIM;
        const float* f1w = fc1_w + (size_t)l * C_DIM * HID_DIM;
        const float* f1b = fc1_b + (size_t)l * HID_DIM;
        const float* f2w = fc2_w + (size_t)l * HID_DIM * C_DIM;
        const float* f2b = fc2_b + (size_t)l * C_DIM;

        // all 4 weight transposes in one dispatch
        TP4 tp{qw, pw, f1w, f2w, wq, wp, w1, w2};
        transpose4_kernel<<<6912, 256, 0, stream>>>(tp);

        // qkv (256x256 pipelined, bf16 out)
        ln_kernel<true><<<NTOK, 256, 0, stream>>>(h, l1g, l1b, y_bf);
        gemm256<false><<<dim3(3 * C_DIM / 256, (NTOK + 255) / 256), 512, 0, stream>>>(
            y_bf, wq, qbs, qkv_bf, NTOK, 3 * C_DIM, C_DIM);

        // attention
        rope_qkv_kernel<<<dim3(14, BATCH * NHEAD), 256, 0, stream>>>(qkv_bf, qb, kb, vtb);
        attn_mfma_kernel<<<dim3(13, BATCH * NHEAD), 256, 0, stream>>>(qb, kb, vtb, y_bf);

        // proj (+res into h)
        gemm_mfma<64, false, true, false><<<dim3(C_DIM / 64, NTOK / 128), 256, 0, stream>>>(
            y_bf, wp, pb, h, h, NTOK, C_DIM, C_DIM);

        // mlp
        ln_kernel<true><<<NTOK, 256, 0, stream>>>(h, l2g, l2b, y_bf);
        gemm256<true><<<dim3(HID_DIM / 256, (NTOK + 255) / 256), 512, 0, stream>>>(
            y_bf, w1, f1b, big_bf, NTOK, HID_DIM, C_DIM);
        gemm_mfma<64, false, true, false><<<dim3(C_DIM / 64, NTOK / 128), 256, 0, stream>>>(
            big_bf, w2, f2b, h, h, NTOK, C_DIM, HID_DIM);
    }

    ln_kernel<false><<<NTOK, 256, 0, stream>>>(h, lnf_g, lnf_b, d_out);
}

// Round 2
// 2644.888 us; speedup vs baseline: 1.2258x; 1.2258x over previous
//
#include <hip/hip_runtime.h>
#include <hip/hip_bf16.h>
#include <math.h>

#define S_LEN   800
#define SP_LEN  896              // padded to 7*128 for K/V
#define C_DIM   768
#define NHEAD   12
#define DHEAD   64
#define HID_DIM 3072
#define BATCH   4
#define NTOK    (BATCH * S_LEN)   // 3200
#define DEPTH_N 12

using bf16x8 = __attribute__((ext_vector_type(8))) short;
using f32x4  = __attribute__((ext_vector_type(4))) float;

__device__ inline short f2bf(float x) {
    unsigned u = __builtin_bit_cast(unsigned, x);
    u += 0x7fff + ((u >> 16) & 1);          // RNE
    return (short)(u >> 16);
}
__device__ inline float bf2f(short x) {
    unsigned u = ((unsigned)(unsigned short)x) << 16;
    return __builtin_bit_cast(float, u);
}

typedef const __attribute__((address_space(1))) void* gas_ptr;
typedef __attribute__((address_space(3))) void* las_ptr;
__device__ inline void async_copy16(const void* g, void* l) {
    __builtin_amdgcn_global_load_lds((gas_ptr)g, (las_ptr)l, 16, 0, 0);
}

// Bijective XCD-chunk remap (m204): blocks with id%8==x form one contiguous
// tile chunk -> per-XCD L2 panel reuse. Valid for any nwg >= 8.
__device__ inline int xcd_remap(int bid, int nwg) {
    int x = bid & 7, q = nwg >> 3, r = nwg & 7;
    int base = (x < r) ? x * (q + 1) : r * (q + 1) + (x - r) * q;
    return base + (bid >> 3);
}

// ---------------------------------------------------------------------------
// Batched transpose + convert for all 4 per-layer weights.
// W fp32 [K][N] -> Wt bf16 [N][K].
// ---------------------------------------------------------------------------
struct TP4 {
    const float *qw, *pw, *f1, *f2;
    short *wq, *wp, *w1, *w2;
};

template <int K, int N>
__device__ __forceinline__ void tc_tile(const float* __restrict__ W,
                                        short* __restrict__ Wt, int t) {
    __shared__ float tile[32][33];
    int nb = t % (N / 32), kb = t / (N / 32);
    int k0 = kb * 32, n0 = nb * 32;
    int tx = threadIdx.x & 31, ty = threadIdx.x >> 5;   // 32 x 8
#pragma unroll
    for (int i = ty; i < 32; i += 8)
        tile[i][tx] = W[(size_t)(k0 + i) * N + n0 + tx];
    __syncthreads();
#pragma unroll
    for (int i = ty; i < 32; i += 8)
        Wt[(size_t)(n0 + i) * K + k0 + tx] = f2bf(tile[tx][i]);
}

__global__ __launch_bounds__(256)
void transpose4_kernel(TP4 p) {
    int t = blockIdx.x;
    if (t < 1728)          tc_tile<768, 2304>(p.qw, p.wq, t);            // 24*72
    else if (t < 2304)     tc_tile<768, 768>(p.pw, p.wp, t - 1728);      // 24*24
    else if (t < 4608)     tc_tile<768, 3072>(p.f1, p.w1, t - 2304);     // 24*96
    else                   tc_tile<3072, 768>(p.f2, p.w2, t - 4608);     // 96*24
}

__global__ void convert_bf_kernel(const float* __restrict__ a, short* __restrict__ o, int n) {
    int i = blockIdx.x * 256 + threadIdx.x;
    if (i < n) o[i] = f2bf(a[i]);
}

// ---------------------------------------------------------------------------
// im2col (bf16 out) for the dual patch embed.
// ---------------------------------------------------------------------------
__global__ void im2col_kernel(const float* __restrict__ x, short* __restrict__ A) {
    int idx = blockIdx.x * 256 + threadIdx.x;          // 3200*768
    if (idx >= NTOK * 768) return;
    int kk = idx % 768;
    int s  = (idx / 768) % S_LEN;
    int b  = idx / (768 * S_LEN);
    int c  = kk / 256;
    int i  = (kk / 16) % 16;
    int j  = kk % 16;
    int half = s / 400, ss = s % 400;
    int hg = ss / 20, wg = ss % 20;
    int ch = half * 3 + c;
    A[idx] = f2bf(x[((size_t)(b * 6 + ch) * 320 + hg * 16 + i) * 320 + wg * 16 + j]);
}

// ---------------------------------------------------------------------------
// bf16 MFMA GEMM: C = A[M,K] @ Bt[N,K]^T + bias (+res)(+GELU).
// BM=128, BK=64, 256 thr. XOR-swizzled LDS; XCD-chunk block remap (T1).
// ---------------------------------------------------------------------------
template <int BN, bool GELU, bool RES, bool OBF>
__global__ __launch_bounds__(256)
void gemm_mfma(const short* __restrict__ A, const short* __restrict__ Bt,
               const float* __restrict__ bias, const float* __restrict__ res,
               void* __restrict__ Cout, int M, int N, int K) {
    constexpr int BM = 128, BK = 64;
    constexpr int TI = (BN == 128) ? 4 : 2;
    constexpr int TJ = 4;
    constexpr int ACALLS = BM * BK / (8 * 64);   // 16
    constexpr int BCALLS = BN * BK / (8 * 64);   // 16 or 8

    __shared__ __align__(16) short As[BM * BK];
    __shared__ __align__(16) short Bs[BN * BK];

    int tid = threadIdx.x;
    int w = tid >> 6, lane = tid & 63;

    int nwg = gridDim.x * gridDim.y;
    int flat = xcd_remap(blockIdx.x + gridDim.x * blockIdx.y, nwg);
    int bx = flat % gridDim.x, by = flat / gridDim.x;
    int m0 = by * BM, n0 = bx * BN;

    int wr = (BN == 128) ? (w >> 1) * 64 : w * 32;
    int wc = (BN == 128) ? (w & 1) * 64 : 0;

    f32x4 acc[TI][TJ];
#pragma unroll
    for (int i = 0; i < TI; ++i)
#pragma unroll
        for (int j = 0; j < TJ; ++j)
            acc[i][j] = (f32x4){0.f, 0.f, 0.f, 0.f};

    int lc = lane & 15, lq = lane >> 4;

    for (int k0 = 0; k0 < K; k0 += BK) {
#pragma unroll
        for (int j = w; j < ACALLS; j += 4) {
            int c = j * 64 + lane;
            int row = c >> 3, p = c & 7, q = p ^ (row & 7);
            async_copy16(A + (size_t)(m0 + row) * K + k0 + q * 8, As + j * 512);
        }
#pragma unroll
        for (int j = w; j < BCALLS; j += 4) {
            int c = j * 64 + lane;
            int row = c >> 3, p = c & 7, q = p ^ (row & 7);
            async_copy16(Bt + (size_t)(n0 + row) * K + k0 + q * 8, Bs + j * 512);
        }
        __syncthreads();

#pragma unroll
        for (int h = 0; h < 2; ++h) {
            bf16x8 afrag[TI], bfrag[TJ];
#pragma unroll
            for (int i = 0; i < TI; ++i) {
                int row = wr + i * 16 + lc;
                afrag[i] = *(const bf16x8*)(As + row * 64 + ((((h << 2) | lq)) ^ (row & 7)) * 8);
            }
#pragma unroll
            for (int j = 0; j < TJ; ++j) {
                int col = wc + j * 16 + lc;
                bfrag[j] = *(const bf16x8*)(Bs + col * 64 + ((((h << 2) | lq)) ^ (col & 7)) * 8);
            }
#pragma unroll
            for (int i = 0; i < TI; ++i)
#pragma unroll
                for (int j = 0; j < TJ; ++j)
                    acc[i][j] = __builtin_amdgcn_mfma_f32_16x16x32_bf16(
                        afrag[i], bfrag[j], acc[i][j], 0, 0, 0);
        }
        __syncthreads();
    }

    int rbase = lq * 4;
#pragma unroll
    for (int i = 0; i < TI; ++i)
#pragma unroll
        for (int j = 0; j < TJ; ++j)
#pragma unroll
            for (int r = 0; r < 4; ++r) {
                int m = m0 + wr + i * 16 + rbase + r;
                int n = n0 + wc + j * 16 + lc;
                float v = acc[i][j][r] + bias[n];
                if (RES) v += res[(size_t)m * N + n];
                if (GELU) v = 0.5f * v * (1.0f + erff(v * 0.70710678118654752f));
                if (OBF) ((short*)Cout)[(size_t)m * N + n] = f2bf(v);
                else     ((float*)Cout)[(size_t)m * N + n] = v;
            }
}

// ---------------------------------------------------------------------------
// LayerNorm (unchanged)
// ---------------------------------------------------------------------------
template <bool OBF>
__global__ __launch_bounds__(256)
void ln_kernel(const float* __restrict__ x, const float* __restrict__ g,
               const float* __restrict__ bta, void* __restrict__ yv) {
    int row = blockIdx.x;
    const float* xr = x + (size_t)row * C_DIM;
    int tid = threadIdx.x;

    float v0 = xr[tid], v1 = xr[tid + 256], v2 = xr[tid + 512];
    float s  = v0 + v1 + v2;
    float sq = v0 * v0 + v1 * v1 + v2 * v2;
#pragma unroll
    for (int off = 32; off; off >>= 1) {
        s  += __shfl_down(s, off);
        sq += __shfl_down(sq, off);
    }
    __shared__ float red1[4], red2[4];
    __shared__ float mean_s, rstd_s;
    int wv = tid / 64, lane = tid % 64;
    if (lane == 0) { red1[wv] = s; red2[wv] = sq; }
    __syncthreads();
    if (tid == 0) {
        float S1 = red1[0] + red1[1] + red1[2] + red1[3];
        float S2 = red2[0] + red2[1] + red2[2] + red2[3];
        float m = S1 / (float)C_DIM;
        float var = S2 / (float)C_DIM - m * m;
        mean_s = m;
        rstd_s = rsqrtf(var + 1e-6f);
    }
    __syncthreads();
    float m = mean_s, r = rstd_s;
    float o0 = (v0 - m) * r * g[tid]       + bta[tid];
    float o1 = (v1 - m) * r * g[tid + 256] + bta[tid + 256];
    float o2 = (v2 - m) * r * g[tid + 512] + bta[tid + 512];
    if (OBF) {
        short* yr = (short*)yv + (size_t)row * C_DIM;
        yr[tid] = f2bf(o0); yr[tid + 256] = f2bf(o1); yr[tid + 512] = f2bf(o2);
    } else {
        float* yr = (float*)yv + (size_t)row * C_DIM;
        yr[tid] = o0; yr[tid + 256] = o1; yr[tid + 512] = o2;
    }
}

// ---------------------------------------------------------------------------
// RoPE + split from bf16 qkv (tok, 2304) ->
//   qb/kb: (bh, s[896], dh) bf16 (q pre-scaled by 0.125*log2e), vtb: (bh, dh, s[896])
// grid (48, 14): blockIdx.x = bh so all tiles of one (b,h) land on one XCD
// (48 % 8 == 0) and attention reads them from that XCD's L2.
// ---------------------------------------------------------------------------
__global__ __launch_bounds__(256)
void rope_qkv_kernel(const short* __restrict__ qkv, short* __restrict__ qb,
                     short* __restrict__ kb, short* __restrict__ vtb) {
    int bh = blockIdx.x;           // 0..47
    int st = blockIdx.y;           // 0..13
    int b = bh / NHEAD, h = bh % NHEAD;
    int s0 = st * 64;

    __shared__ __align__(16) short vlds[64][72];

    int tid = threadIdx.x;
    int sl = tid >> 2;             // s row within tile
    int dc = (tid & 3) * 16;       // d chunk base
    int s = s0 + sl;

    short qo[16], ko[16];
    if (s < S_LEN) {
        const short* base = qkv + ((size_t)(b * S_LEN + s)) * (3 * C_DIM) + h * DHEAD + dc;
        short qsh[16], ksh[16], vsh[16];
        *(bf16x8*)(qsh)     = *(const bf16x8*)(base);
        *(bf16x8*)(qsh + 8) = *(const bf16x8*)(base + 8);
        *(bf16x8*)(ksh)     = *(const bf16x8*)(base + C_DIM);
        *(bf16x8*)(ksh + 8) = *(const bf16x8*)(base + C_DIM + 8);
        *(bf16x8*)(vsh)     = *(const bf16x8*)(base + 2 * C_DIM);
        *(bf16x8*)(vsh + 8) = *(const bf16x8*)(base + 2 * C_DIM + 8);
        float qv[16], kv[16];
#pragma unroll
        for (int i = 0; i < 16; ++i) { qv[i] = bf2f(qsh[i]); kv[i] = bf2f(ksh[i]); }
#pragma unroll
        for (int i = 0; i < 16; ++i) {
            int d = dc + i;
            float ang = (float)s * exp2f(-(float)(d & 31) * 0.41524101186092029f); // log2(1e4)/16
            float c = cosf(ang), sn = sinf(ang);
            float sign = (i & 1) ? 1.0f : -1.0f;
            qo[i] = f2bf((qv[i] * c + sign * qv[i ^ 1] * sn) * 0.18033688011112042f);
            ko[i] = f2bf(kv[i] * c + sign * kv[i ^ 1] * sn);
        }
        *(bf16x8*)&vlds[sl][dc]     = *(bf16x8*)(vsh);
        *(bf16x8*)&vlds[sl][dc + 8] = *(bf16x8*)(vsh + 8);
    } else {
#pragma unroll
        for (int i = 0; i < 16; ++i) { qo[i] = 0; ko[i] = 0; vlds[sl][dc + i] = 0; }
    }
    {
        short* qd = qb + ((size_t)bh * SP_LEN + s) * DHEAD + dc;
        short* kd = kb + ((size_t)bh * SP_LEN + s) * DHEAD + dc;
        *(bf16x8*)(qd)     = *(bf16x8*)(qo);
        *(bf16x8*)(qd + 8) = *(bf16x8*)(qo + 8);
        *(bf16x8*)(kd)     = *(bf16x8*)(ko);
        *(bf16x8*)(kd + 8) = *(bf16x8*)(ko + 8);
    }
    __syncthreads();
    {
        int dr = tid >> 2, sc = (tid & 3) * 16;
        short vo[16];
#pragma unroll
        for (int i = 0; i < 16; ++i) vo[i] = vlds[sc + i][dr];
        short* vd = vtb + ((size_t)bh * DHEAD + dr) * SP_LEN + s0 + sc;
        *(bf16x8*)(vd)     = *(bf16x8*)(vo);
        *(bf16x8*)(vd + 8) = *(bf16x8*)(vo + 8);
    }
}

// ---------------------------------------------------------------------------
// Flash attention, bf16 MFMA, K-tile=128, XOR-swizzled LDS.
// grid (48, 13): blockIdx.x = bh -> all 13 q-tiles of a head on one XCD
// (K/V L2-resident, ~2.1 MB/XCD working set). Q frags hoisted; setprio (T5)
// around MFMA clusters.
// ---------------------------------------------------------------------------
__global__ __launch_bounds__(256)
void attn_mfma_kernel(const short* __restrict__ qb, const short* __restrict__ kb,
                      const short* __restrict__ vtb, short* __restrict__ o) {
    int bh = blockIdx.x;           // 0..47
    int qt = blockIdx.y;           // 0..12
    int b = bh / NHEAD, h = bh % NHEAD;
    int m0 = qt * 64;

    __shared__ __align__(16) short Qs[64 * 64];
    __shared__ __align__(16) short Ks[128 * 64];
    __shared__ __align__(16) short Vts[64 * 128];
    __shared__ __align__(16) short Ps[64 * 136];

    int tid = threadIdx.x;
    int w = tid >> 6, lane = tid & 63;
    int lc = lane & 15, lq = lane >> 4;
    int kq = lq * 8;

    const short* qbase = qb + (size_t)bh * SP_LEN * DHEAD;
    const short* kbase = kb + (size_t)bh * SP_LEN * DHEAD;
    const short* vbase = vtb + (size_t)bh * DHEAD * SP_LEN;

    f32x4 oacc[4];
#pragma unroll
    for (int t = 0; t < 4; ++t) oacc[t] = (f32x4){0.f, 0.f, 0.f, 0.f};
    float mrow[4] = {-3.0e38f, -3.0e38f, -3.0e38f, -3.0e38f};
    float lrow[4] = {0.f, 0.f, 0.f, 0.f};

    // stage Q once (swizzled)
#pragma unroll
    for (int j = w; j < 8; j += 4) {
        int c = j * 64 + lane;
        int row = c >> 3, p = c & 7, q = p ^ (row & 7);
        async_copy16(qbase + (size_t)(m0 + row) * DHEAD + q * 8, Qs + j * 512);
    }

    bf16x8 aq0, aq1;

    for (int it = 0; it < 7; ++it) {
        int kt = it * 128;
#pragma unroll
        for (int j = w; j < 16; j += 4) {
            int c = j * 64 + lane;
            int row = c >> 3, p = c & 7, q = p ^ (row & 7);
            async_copy16(kbase + (size_t)(kt + row) * DHEAD + q * 8, Ks + j * 512);
        }
#pragma unroll
        for (int j = w; j < 16; j += 4) {
            int c = j * 64 + lane;
            int d = c >> 4, p = c & 15, sq = p ^ (d & 15);
            async_copy16(vbase + (size_t)d * SP_LEN + kt + sq * 8, Vts + j * 512);
        }
        __syncthreads();

        int nt = (it < 6) ? 8 : 2;     // valid 16-col tiles

        if (it == 0) {                 // loop-invariant Q fragments
            int qrow = w * 16 + lc;
            aq0 = *(const bf16x8*)(Qs + qrow * 64 + ((lq) ^ (qrow & 7)) * 8);
            aq1 = *(const bf16x8*)(Qs + qrow * 64 + ((4 | lq) ^ (qrow & 7)) * 8);
        }

        f32x4 sacc[8];
        __builtin_amdgcn_s_setprio(1);
        for (int t = 0; t < nt; ++t) {
            int kr = t * 16 + lc;
            bf16x8 bk0 = *(const bf16x8*)(Ks + kr * 64 + ((lq) ^ (kr & 7)) * 8);
            bf16x8 bk1 = *(const bf16x8*)(Ks + kr * 64 + ((4 | lq) ^ (kr & 7)) * 8);
            f32x4 z = (f32x4){0.f, 0.f, 0.f, 0.f};
            z = __builtin_amdgcn_mfma_f32_16x16x32_bf16(aq0, bk0, z, 0, 0, 0);
            z = __builtin_amdgcn_mfma_f32_16x16x32_bf16(aq1, bk1, z, 0, 0, 0);
            sacc[t] = z;
        }
        __builtin_amdgcn_s_setprio(0);

        float rmax[4];
#pragma unroll
        for (int r = 0; r < 4; ++r) {
            float m = sacc[0][r];
            for (int t = 1; t < nt; ++t) m = fmaxf(m, sacc[t][r]);
            rmax[r] = m;
        }
#pragma unroll
        for (int off = 1; off < 16; off <<= 1)
#pragma unroll
            for (int r = 0; r < 4; ++r)
                rmax[r] = fmaxf(rmax[r], __shfl_xor(rmax[r], off));

        float alpha[4], rsum[4] = {0.f, 0.f, 0.f, 0.f};
#pragma unroll
        for (int r = 0; r < 4; ++r) {
            float mnew = fmaxf(mrow[r], rmax[r]);
            alpha[r] = exp2f(mrow[r] - mnew);
            mrow[r] = mnew;
        }
        for (int t = 0; t < nt; ++t) {
#pragma unroll
            for (int r = 0; r < 4; ++r) {
                float p = exp2f(sacc[t][r] - mrow[r]);
                rsum[r] += p;
                Ps[(w * 16 + lq * 4 + r) * 136 + t * 16 + lc] = f2bf(p);
            }
        }
#pragma unroll
        for (int off = 1; off < 16; off <<= 1)
#pragma unroll
            for (int r = 0; r < 4; ++r)
                rsum[r] += __shfl_xor(rsum[r], off);
#pragma unroll
        for (int r = 0; r < 4; ++r) lrow[r] = lrow[r] * alpha[r] + rsum[r];
#pragma unroll
        for (int t = 0; t < 4; ++t)
#pragma unroll
            for (int r = 0; r < 4; ++r) oacc[t][r] *= alpha[r];

        int nk = (nt == 8) ? 4 : 1;
        __builtin_amdgcn_s_setprio(1);
        for (int kstep = 0; kstep < nk; ++kstep) {
            bf16x8 ap = *(const bf16x8*)(Ps + (w * 16 + lc) * 136 + kstep * 32 + kq);
#pragma unroll
            for (int t = 0; t < 4; ++t) {
                int dr = t * 16 + lc;
                bf16x8 bv = *(const bf16x8*)(Vts + dr * 128 + ((((kstep << 2) | lq)) ^ (dr & 15)) * 8);
                oacc[t] = __builtin_amdgcn_mfma_f32_16x16x32_bf16(ap, bv, oacc[t], 0, 0, 0);
            }
        }
        __builtin_amdgcn_s_setprio(0);
        __syncthreads();
    }

    float inv_l[4];
#pragma unroll
    for (int r = 0; r < 4; ++r) inv_l[r] = 1.0f / lrow[r];
#pragma unroll
    for (int t = 0; t < 4; ++t)
#pragma unroll
        for (int r = 0; r < 4; ++r) {
            int row = w * 16 + lq * 4 + r;
            int s = m0 + row;
            if (s < S_LEN) {
                int n = t * 16 + lc;
                o[((size_t)(b * S_LEN + s)) * C_DIM + h * DHEAD + n] = f2bf(oacc[t][r] * inv_l[r]);
            }
        }
}

// ---------------------------------------------------------------------------
// Host launcher
// ---------------------------------------------------------------------------
extern "C" void kernel_launch(void* const* d_in, const int* in_sizes, int n_in,
                              void* d_out, int out_size, void* d_ws, size_t ws_size,
                              hipStream_t stream) {
    const float* x      = (const float*)d_in[0];
    const float* conv_w = (const float*)d_in[1];
    const float* conv_b = (const float*)d_in[2];
    const float* ln1_g  = (const float*)d_in[3];
    const float* ln1_b  = (const float*)d_in[4];
    const float* qkv_w  = (const float*)d_in[5];
    const float* qkv_b  = (const float*)d_in[6];
    const float* proj_w = (const float*)d_in[7];
    const float* proj_b = (const float*)d_in[8];
    const float* ln2_g  = (const float*)d_in[9];
    const float* ln2_b  = (const float*)d_in[10];
    const float* fc1_w  = (const float*)d_in[11];
    const float* fc1_b  = (const float*)d_in[12];
    const float* fc2_w  = (const float*)d_in[13];
    const float* fc2_b  = (const float*)d_in[14];
    const float* lnf_g  = (const float*)d_in[15];
    const float* lnf_b  = (const float*)d_in[16];

    const size_t NTC = (size_t)NTOK * C_DIM;
    const size_t HSD = (size_t)BATCH * NHEAD * SP_LEN * DHEAD;  // 2,752,512
    float* ws = (float*)d_ws;
    float* h       = ws;                              // (B,S,C) f32
    short* qkv_bf  = (short*)(h + NTC);               // (B,S,3C) bf16
    short* qb      = qkv_bf + (size_t)NTOK * 3 * C_DIM;
    short* kb      = qb + HSD;
    short* vtb     = kb + HSD;
    short* y_bf    = vtb + HSD;                       // (B,S,C) bf16
    short* big_bf  = y_bf + NTC;                      // (B,S,HID) bf16 / im2col
    short* wq      = big_bf + (size_t)NTOK * HID_DIM; // (3C, C) bf16
    short* wp      = wq + (size_t)3 * C_DIM * C_DIM;  // (C, C)
    short* w1      = wp + (size_t)C_DIM * C_DIM;      // (HID, C)
    short* w2      = w1 + (size_t)C_DIM * HID_DIM;    // (C, HID)
    short* embed_wt = w2 + (size_t)HID_DIM * C_DIM;   // (C, C)

    // ---- patch embed ----
    convert_bf_kernel<<<(768 * 768 + 255) / 256, 256, 0, stream>>>(conv_w, embed_wt, 768 * 768);
    im2col_kernel<<<(NTOK * 768 + 255) / 256, 256, 0, stream>>>(x, big_bf);
    gemm_mfma<64, false, false, false><<<dim3(C_DIM / 64, NTOK / 128), 256, 0, stream>>>(
        big_bf, embed_wt, conv_b, nullptr, h, NTOK, C_DIM, C_DIM);

    for (int l = 0; l < DEPTH_N; ++l) {
        const float* l1g = ln1_g + (size_t)l * C_DIM;
        const float* l1b = ln1_b + (size_t)l * C_DIM;
        const float* qw  = qkv_w + (size_t)l * C_DIM * 3 * C_DIM;
        const float* qbs = qkv_b + (size_t)l * 3 * C_DIM;
        const float* pw  = proj_w + (size_t)l * C_DIM * C_DIM;
        const float* pb  = proj_b + (size_t)l * C_DIM;
        const float* l2g = ln2_g + (size_t)l * C_DIM;
        const float* l2b = ln2_b + (size_t)l * C_DIM;
        const float* f1w = fc1_w + (size_t)l * C_DIM * HID_DIM;
        const float* f1b = fc1_b + (size_t)l * HID_DIM;
        const float* f2w = fc2_w + (size_t)l * HID_DIM * C_DIM;
        const float* f2b = fc2_b + (size_t)l * C_DIM;

        // all 4 weight transposes in one dispatch
        TP4 tp{qw, pw, f1w, f2w, wq, wp, w1, w2};
        transpose4_kernel<<<6912, 256, 0, stream>>>(tp);

        // qkv (bf16 out)
        ln_kernel<true><<<NTOK, 256, 0, stream>>>(h, l1g, l1b, y_bf);
        gemm_mfma<128, false, false, true><<<dim3(3 * C_DIM / 128, NTOK / 128), 256, 0, stream>>>(
            y_bf, wq, qbs, nullptr, qkv_bf, NTOK, 3 * C_DIM, C_DIM);

        // attention (bh-major grids: per-head XCD locality)
        rope_qkv_kernel<<<dim3(BATCH * NHEAD, 14), 256, 0, stream>>>(qkv_bf, qb, kb, vtb);
        attn_mfma_kernel<<<dim3(BATCH * NHEAD, 13), 256, 0, stream>>>(qb, kb, vtb, y_bf);

        // proj (+res into h)
        gemm_mfma<64, false, true, false><<<dim3(C_DIM / 64, NTOK / 128), 256, 0, stream>>>(
            y_bf, wp, pb, h, h, NTOK, C_DIM, C_DIM);

        // mlp
        ln_kernel<true><<<NTOK, 256, 0, stream>>>(h, l2g, l2b, y_bf);
        gemm_mfma<128, true, false, true><<<dim3(HID_DIM / 128, NTOK / 128), 256, 0, stream>>>(
            y_bf, w1, f1b, nullptr, big_bf, NTOK, HID_DIM, C_DIM);
        gemm_mfma<64, false, true, false><<<dim3(C_DIM / 64, NTOK / 128), 256, 0, stream>>>(
            big_bf, w2, f2b, h, h, NTOK, C_DIM, HID_DIM);
    }

    ln_kernel<false><<<NTOK, 256, 0, stream>>>(h, lnf_g, lnf_b, d_out);
}